// Round 1
// baseline (6095.729 us; speedup 1.0000x reference)
//
#include <hip/hip_runtime.h>
#include <cstdint>
#include <cstddef>

// ---------------- types ----------------
typedef _Float16 half8 __attribute__((ext_vector_type(8)));
typedef float floatx4 __attribute__((ext_vector_type(4)));

typedef __attribute__((address_space(3))) unsigned lds_u32;
typedef const __attribute__((address_space(1))) unsigned glb_u32;

#define BM 128
#define BN 128
#define BK 32

__device__ __forceinline__ void glds16(const void* g, void* l) {
    // async global->LDS, 16B per lane; LDS dest = wave-uniform base + lane*16
    __builtin_amdgcn_global_load_lds((glb_u32*)g, (lds_u32*)l, 16, 0, 0);
}

__device__ __forceinline__ float fast_tanh(float x) {
    float ax = fabsf(x);
    float e  = __expf(-2.0f * ax);
    float t  = (1.0f - e) / (1.0f + e);
    return x < 0.0f ? -t : t;
}

// ---------------- GEMM core: C[128x128] = A[BMxK] * BT[BNxK]^T ----------------
// A row-major M x K (fp16), BT row-major N x K (fp16, i.e. B transposed).
// acc[i][j] -> m-tile i, n-tile j; each 16x16; wave grid 2x2 (64x64 per wave).
__device__ __forceinline__ void gemm_acc(const _Float16* __restrict__ A,
                                         const _Float16* __restrict__ BT,
                                         int K, floatx4 acc[4][4]) {
    __shared__ __align__(16) _Float16 As[BM * BK];
    __shared__ __align__(16) _Float16 Bs[BN * BK];

    const int tid  = threadIdx.x;
    const int lane = tid & 63;
    const int wid  = tid >> 6;                 // 0..3
    const size_t m0 = (size_t)blockIdx.x * BM;
    const size_t n0 = (size_t)blockIdx.y * BN;

    const int lrow = lane >> 2;                // 0..15 : row within 16-row issue
    const int lkk  = (lane & 3) * 8;           // half-elem offset within 32-elem row

    const int quad = lane >> 4;                // 0..3
    const int l16  = lane & 15;
    const int wm   = (wid >> 1) * 64;          // wave m-offset in tile
    const int wn   = (wid & 1) * 64;           // wave n-offset in tile

#pragma unroll
    for (int i = 0; i < 4; ++i)
#pragma unroll
        for (int j = 0; j < 4; ++j)
            acc[i][j] = 0.0f;

    for (int k0 = 0; k0 < K; k0 += BK) {
        // stage: each wave loads 32 rows of As and 32 rows of Bs (2 issues each)
#pragma unroll
        for (int i = 0; i < 2; ++i) {
            const int r = wid * 32 + i * 16;   // wave-uniform base row
            glds16(A  + (m0 + r + lrow) * (size_t)K + k0 + lkk, As + (size_t)r * BK);
            glds16(BT + (n0 + r + lrow) * (size_t)K + k0 + lkk, Bs + (size_t)r * BK);
        }
        __syncthreads();   // drains vmcnt(0) before barrier

        half8 av[4], bv[4];
#pragma unroll
        for (int i = 0; i < 4; ++i) {
            av[i] = *(const half8*)(As + (wm + i * 16 + l16) * BK + quad * 8);
            bv[i] = *(const half8*)(Bs + (wn + i * 16 + l16) * BK + quad * 8);
        }
#pragma unroll
        for (int i = 0; i < 4; ++i)
#pragma unroll
            for (int j = 0; j < 4; ++j)
                acc[i][j] = __builtin_amdgcn_mfma_f32_16x16x32_f16(av[i], bv[j], acc[i][j], 0, 0, 0);
        __syncthreads();
    }
}

// C/D layout (verified m89/m91): col = lane&15, row = quad*4 + reg.

// ---------------- GEMM + bias (+ t*brow) + tanh -> fp16 out ----------------
template <bool WITH_T>
__global__ __launch_bounds__(256)
void gemm_bias_tanh(const _Float16* __restrict__ A, const _Float16* __restrict__ BT,
                    _Float16* __restrict__ out, const float* __restrict__ bias,
                    const float* __restrict__ brow, float t, int N, int K) {
    floatx4 acc[4][4];
    gemm_acc(A, BT, K, acc);

    const int tid  = threadIdx.x;
    const int lane = tid & 63;
    const int wid  = tid >> 6;
    const int quad = lane >> 4;
    const int l16  = lane & 15;
    const size_t m0 = (size_t)blockIdx.x * BM + (size_t)(wid >> 1) * 64;
    const size_t n0 = (size_t)blockIdx.y * BN + (size_t)(wid & 1) * 64;

#pragma unroll
    for (int j = 0; j < 4; ++j) {
        const size_t col = n0 + j * 16 + l16;
        float b = bias[col];
        if (WITH_T) b += t * brow[col];
#pragma unroll
        for (int i = 0; i < 4; ++i) {
            const size_t rbase = m0 + i * 16 + quad * 4;
#pragma unroll
            for (int r = 0; r < 4; ++r) {
                out[(rbase + r) * (size_t)N + col] = (_Float16)fast_tanh(acc[i][j][r] + b);
            }
        }
    }
}

// ---------------- GEMM3 + fused RK4 stage update ----------------
// stage 0: accb = k;            x = fp16(h + c*k)
// stage 1: accb += 2k;          x = fp16(h + c*k)      (c = dt/2)
// stage 2: accb += 2k;          x = fp16(h + c*k)      (c = dt)
// stage 3: h += dt/6*(accb+k);  x = fp16(h)
__global__ __launch_bounds__(256)
void gemm_k_stage(const _Float16* __restrict__ A, const _Float16* __restrict__ BT,
                  const float* __restrict__ bias, float* __restrict__ hstate,
                  float* __restrict__ accb, _Float16* __restrict__ x,
                  int stage, float c, float dt6, int N, int K) {
    floatx4 acc[4][4];
    gemm_acc(A, BT, K, acc);

    const int tid  = threadIdx.x;
    const int lane = tid & 63;
    const int wid  = tid >> 6;
    const int quad = lane >> 4;
    const int l16  = lane & 15;
    const size_t m0 = (size_t)blockIdx.x * BM + (size_t)(wid >> 1) * 64;
    const size_t n0 = (size_t)blockIdx.y * BN + (size_t)(wid & 1) * 64;

#pragma unroll
    for (int j = 0; j < 4; ++j) {
        const size_t col = n0 + j * 16 + l16;
        const float b = bias[col];
#pragma unroll
        for (int i = 0; i < 4; ++i) {
            const size_t rbase = m0 + i * 16 + quad * 4;
#pragma unroll
            for (int r = 0; r < 4; ++r) {
                const size_t idx = (rbase + r) * (size_t)N + col;
                const float k = acc[i][j][r] + b;
                if (stage == 0) {
                    accb[idx] = k;
                    x[idx] = (_Float16)(hstate[idx] + c * k);
                } else if (stage < 3) {
                    accb[idx] += 2.0f * k;
                    x[idx] = (_Float16)(hstate[idx] + c * k);
                } else {
                    const float hn = hstate[idx] + dt6 * (accb[idx] + k);
                    hstate[idx] = hn;
                    x[idx] = (_Float16)hn;
                }
            }
        }
    }
}

// ---------------- setup kernels ----------------
// WT[n*K + k] = (fp16) W[k*N + n]   (W is K x N fp32, row stride N)
__global__ void convT(const float* __restrict__ W, _Float16* __restrict__ WT,
                      int K, int N) {
    const int n = blockIdx.x * 256 + threadIdx.x;
    const int k = blockIdx.y;
    if (n < N) WT[(size_t)n * K + k] = (_Float16)W[(size_t)k * N + n];
}

__global__ void copy_row(const float* __restrict__ W1, float* __restrict__ w1row, int N) {
    const int n = blockIdx.x * 256 + threadIdx.x;
    if (n < N) w1row[n] = W1[(size_t)1024 * N + n];
}

__global__ void init_h(const float* __restrict__ h0, float* __restrict__ hstate,
                       _Float16* __restrict__ x, int n) {
    const int i = blockIdx.x * 256 + threadIdx.x;
    if (i < n) {
        const float v = h0[i];
        hstate[i] = v;
        x[i] = (_Float16)v;
    }
}

// ---------------- launch ----------------
extern "C" void kernel_launch(void* const* d_in, const int* in_sizes, int n_in,
                              void* d_out, int out_size, void* d_ws, size_t ws_size,
                              hipStream_t stream) {
    const int B = 4096, H = 1024, H2 = 2048;

    const float* h0 = (const float*)d_in[0];
    const float* W1 = (const float*)d_in[1];  // (1025, 2048)
    const float* b1 = (const float*)d_in[2];  // (2048,)
    const float* W2 = (const float*)d_in[3];  // (2048, 2048)
    const float* b2 = (const float*)d_in[4];  // (2048,)
    const float* W3 = (const float*)d_in[5];  // (2048, 1024)
    const float* b3 = (const float*)d_in[6];  // (1024,)

    float* hstate = (float*)d_out;            // B*H fp32 state, final answer

    char* ws = (char*)d_ws;
    _Float16* x    = (_Float16*)ws; ws += (size_t)B * H  * 2;  // GEMM1 input
    _Float16* a1   = (_Float16*)ws; ws += (size_t)B * H2 * 2;  // layer-1 act
    _Float16* a2   = (_Float16*)ws; ws += (size_t)B * H2 * 2;  // layer-2 act
    float*    accb = (float*)ws;    ws += (size_t)B * H  * 4;  // RK4 k-accum
    _Float16* W1T  = (_Float16*)ws; ws += (size_t)H2 * H  * 2; // (2048,1024)
    _Float16* W2T  = (_Float16*)ws; ws += (size_t)H2 * H2 * 2; // (2048,2048)
    _Float16* W3T  = (_Float16*)ws; ws += (size_t)H  * H2 * 2; // (1024,2048)
    float*   w1row = (float*)ws;    ws += (size_t)H2 * 4;      // t-row of W1, fp32

    // weight conversion + transpose (runs every call; weights restored by harness)
    convT<<<dim3(H2 / 256, H),  256, 0, stream>>>(W1, W1T, H,  H2);
    convT<<<dim3(H2 / 256, H2), 256, 0, stream>>>(W2, W2T, H2, H2);
    convT<<<dim3(H  / 256, H2), 256, 0, stream>>>(W3, W3T, H2, H);
    copy_row<<<dim3(H2 / 256), 256, 0, stream>>>(W1, w1row, H2);
    init_h<<<dim3((B * H + 255) / 256), 256, 0, stream>>>(h0, hstate, x, B * H);

    const float dt  = 0.1f;
    const float dt2 = 0.05f;
    const float dt6 = dt / 6.0f;

    const dim3 blk(256);
    const dim3 g1grid(B / BM, H2 / BN);   // (32,16)
    const dim3 g2grid(B / BM, H2 / BN);   // (32,16)
    const dim3 g3grid(B / BM, H  / BN);   // (32,8)

    for (int s = 0; s < 10; ++s) {
        const float ti = (float)s * dt;

        // k1 = f(ti, h)
        gemm_bias_tanh<true ><<<g1grid, blk, 0, stream>>>(x,  W1T, a1, b1, w1row, ti,        H2, H);
        gemm_bias_tanh<false><<<g2grid, blk, 0, stream>>>(a1, W2T, a2, b2, nullptr, 0.f,     H2, H2);
        gemm_k_stage<<<g3grid, blk, 0, stream>>>(a2, W3T, b3, hstate, accb, x, 0, dt2, dt6,  H,  H2);

        // k2 = f(ti+dt/2, h + dt/2*k1)
        gemm_bias_tanh<true ><<<g1grid, blk, 0, stream>>>(x,  W1T, a1, b1, w1row, ti + dt2,  H2, H);
        gemm_bias_tanh<false><<<g2grid, blk, 0, stream>>>(a1, W2T, a2, b2, nullptr, 0.f,     H2, H2);
        gemm_k_stage<<<g3grid, blk, 0, stream>>>(a2, W3T, b3, hstate, accb, x, 1, dt2, dt6,  H,  H2);

        // k3 = f(ti+dt/2, h + dt/2*k2)
        gemm_bias_tanh<true ><<<g1grid, blk, 0, stream>>>(x,  W1T, a1, b1, w1row, ti + dt2,  H2, H);
        gemm_bias_tanh<false><<<g2grid, blk, 0, stream>>>(a1, W2T, a2, b2, nullptr, 0.f,     H2, H2);
        gemm_k_stage<<<g3grid, blk, 0, stream>>>(a2, W3T, b3, hstate, accb, x, 2, dt,  dt6,  H,  H2);

        // k4 = f(ti+dt, h + dt*k3); h += dt/6*(k1+2k2+2k3+k4)
        gemm_bias_tanh<true ><<<g1grid, blk, 0, stream>>>(x,  W1T, a1, b1, w1row, ti + dt,   H2, H);
        gemm_bias_tanh<false><<<g2grid, blk, 0, stream>>>(a1, W2T, a2, b2, nullptr, 0.f,     H2, H2);
        gemm_k_stage<<<g3grid, blk, 0, stream>>>(a2, W3T, b3, hstate, accb, x, 3, dt,  dt6,  H,  H2);
    }
}

// Round 2
// 5288.831 us; speedup vs baseline: 1.1526x; 1.1526x over previous
//
#include <hip/hip_runtime.h>
#include <cstdint>
#include <cstddef>

// ---------------- types ----------------
typedef _Float16 half8 __attribute__((ext_vector_type(8)));
typedef float floatx4 __attribute__((ext_vector_type(4)));

typedef __attribute__((address_space(3))) unsigned lds_u32;
typedef const __attribute__((address_space(1))) unsigned glb_u32;

#define BK 32

__device__ __forceinline__ void glds16(const void* g, void* l) {
    // async global->LDS, 16B per lane; LDS dest = wave-uniform base + lane*16
    __builtin_amdgcn_global_load_lds((glb_u32*)g, (lds_u32*)l, 16, 0, 0);
}

__device__ __forceinline__ float fast_tanh(float x) {
    float ax = fabsf(x);
    float e  = __expf(-2.0f * ax);
    float t  = (1.0f - e) / (1.0f + e);
    return x < 0.0f ? -t : t;
}

// ---------------- GEMM core, double-buffered ----------------
// C[TBM x TBN] = A[TBM x K] * BT[TBN x K]^T, both fp16 row-major (BT = B^T).
// 4 waves; wave grid (TBM/(16*MF)) x (TBN/(16*NF)); acc[i][j] = 16x16 tile.
// One barrier per K-iter: prefetch next tile into alt buffer before compute,
// so the vmcnt drain at the next barrier overlaps with this iter's MFMAs.
template <int TBM, int TBN, int MF, int NF>
__device__ __forceinline__ void gemm_acc_db(const _Float16* __restrict__ A,
                                            const _Float16* __restrict__ BT,
                                            int K, floatx4 acc[MF][NF]) {
    constexpr int CW = TBN / (16 * NF);   // waves along n
    static_assert((TBM / (16 * MF)) * CW == 4, "wave layout must use 4 waves");

    __shared__ __align__(16) _Float16 As[2][TBM * BK];
    __shared__ __align__(16) _Float16 Bs[2][TBN * BK];

    const int tid  = threadIdx.x;
    const int lane = tid & 63;
    const int wid  = tid >> 6;
    const size_t m0 = (size_t)blockIdx.x * TBM;
    const size_t n0 = (size_t)blockIdx.y * TBN;

    const int lrow = lane >> 2;            // 0..15: row within a 16-row chunk
    const int lkk  = (lane & 3) * 8;       // fp16-elem offset within 32-elem row
    const int quad = lane >> 4;
    const int l16  = lane & 15;
    const int wm   = (wid / CW) * (16 * MF);
    const int wn   = (wid % CW) * (16 * NF);

#pragma unroll
    for (int i = 0; i < MF; ++i)
#pragma unroll
        for (int j = 0; j < NF; ++j)
            acc[i][j] = 0.0f;

    auto stage = [&](int buf, int k0) {
        // each glds16 issue: 64 lanes x 16B = 16 rows (4 lanes/row of 64B)
#pragma unroll
        for (int c = wid; c < TBM / 16; c += 4) {
            const int r = c * 16;
            glds16(A + (m0 + r + lrow) * (size_t)K + k0 + lkk, &As[buf][r * BK]);
        }
#pragma unroll
        for (int c = wid; c < TBN / 16; c += 4) {
            const int r = c * 16;
            glds16(BT + (n0 + r + lrow) * (size_t)K + k0 + lkk, &Bs[buf][r * BK]);
        }
    };

    stage(0, 0);
    int cur = 0;
    for (int k0 = 0; k0 < K; k0 += BK) {
        __syncthreads();                       // buf[cur] ready (drains vmcnt)
        if (k0 + BK < K) stage(cur ^ 1, k0 + BK);  // overlap with MFMAs below

        half8 av[MF], bv[NF];
#pragma unroll
        for (int i = 0; i < MF; ++i)
            av[i] = *(const half8*)(&As[cur][(wm + i * 16 + l16) * BK + quad * 8]);
#pragma unroll
        for (int j = 0; j < NF; ++j)
            bv[j] = *(const half8*)(&Bs[cur][(wn + j * 16 + l16) * BK + quad * 8]);
#pragma unroll
        for (int i = 0; i < MF; ++i)
#pragma unroll
            for (int j = 0; j < NF; ++j)
                acc[i][j] = __builtin_amdgcn_mfma_f32_16x16x32_f16(av[i], bv[j], acc[i][j], 0, 0, 0);
        cur ^= 1;
    }
}

// C/D layout (verified m89/m91): col = lane&15, row = quad*4 + reg.

// ---------------- GEMM + bias (+ t*brow) + tanh -> fp16 out ----------------
template <bool WITH_T>
__global__ __launch_bounds__(256)
void gemm_bias_tanh(const _Float16* __restrict__ A, const _Float16* __restrict__ BT,
                    _Float16* __restrict__ out, const float* __restrict__ bias,
                    const float* __restrict__ brow, float t, int N, int K) {
    floatx4 acc[4][4];
    gemm_acc_db<128, 128, 4, 4>(A, BT, K, acc);

    const int tid  = threadIdx.x;
    const int lane = tid & 63;
    const int wid  = tid >> 6;
    const int quad = lane >> 4;
    const int l16  = lane & 15;
    const size_t m0 = (size_t)blockIdx.x * 128 + (size_t)(wid / 2) * 64;
    const size_t n0 = (size_t)blockIdx.y * 128 + (size_t)(wid % 2) * 64;

#pragma unroll
    for (int j = 0; j < 4; ++j) {
        const size_t col = n0 + j * 16 + l16;
        float b = bias[col];
        if (WITH_T) b += t * brow[col];
#pragma unroll
        for (int i = 0; i < 4; ++i) {
            const size_t rbase = m0 + i * 16 + quad * 4;
#pragma unroll
            for (int r = 0; r < 4; ++r) {
                out[(rbase + r) * (size_t)N + col] = (_Float16)fast_tanh(acc[i][j][r] + b);
            }
        }
    }
}

// ---------------- GEMM3 (64x128 tile) + fused RK4 stage update ----------------
// stage 0: accb = k;            x = fp16(h + c*k)
// stage 1: accb += 2k;          x = fp16(h + c*k)      (c = dt/2)
// stage 2: accb += 2k;          x = fp16(h + c*k)      (c = dt)
// stage 3: h += dt/6*(accb+k);  x = fp16(h)
__global__ __launch_bounds__(256)
void gemm_k_stage(const _Float16* __restrict__ A, const _Float16* __restrict__ BT,
                  const float* __restrict__ bias, float* __restrict__ hstate,
                  float* __restrict__ accb, _Float16* __restrict__ x,
                  int stage, float c, float dt6, int N, int K) {
    floatx4 acc[4][2];
    gemm_acc_db<64, 128, 4, 2>(A, BT, K, acc);

    const int tid  = threadIdx.x;
    const int lane = tid & 63;
    const int wid  = tid >> 6;
    const int quad = lane >> 4;
    const int l16  = lane & 15;
    // wave layout for <64,128,4,2>: CW=4 -> wm = 0, wn = wid*32
    const size_t m0 = (size_t)blockIdx.x * 64;
    const size_t n0 = (size_t)blockIdx.y * 128 + (size_t)wid * 32;

#pragma unroll
    for (int j = 0; j < 2; ++j) {
        const size_t col = n0 + j * 16 + l16;
        const float b = bias[col];
#pragma unroll
        for (int i = 0; i < 4; ++i) {
            const size_t rbase = m0 + i * 16 + quad * 4;
#pragma unroll
            for (int r = 0; r < 4; ++r) {
                const size_t idx = (rbase + r) * (size_t)N + col;
                const float k = acc[i][j][r] + b;
                if (stage == 0) {
                    accb[idx] = k;
                    x[idx] = (_Float16)(hstate[idx] + c * k);
                } else if (stage < 3) {
                    accb[idx] += 2.0f * k;
                    x[idx] = (_Float16)(hstate[idx] + c * k);
                } else {
                    const float hn = hstate[idx] + dt6 * (accb[idx] + k);
                    hstate[idx] = hn;
                    x[idx] = (_Float16)hn;
                }
            }
        }
    }
}

// ---------------- setup kernels ----------------
// WT[n*K + k] = (fp16) W[k*N + n]   (W is K x N fp32, row stride N)
__global__ void convT(const float* __restrict__ W, _Float16* __restrict__ WT,
                      int K, int N) {
    const int n = blockIdx.x * 256 + threadIdx.x;
    const int k = blockIdx.y;
    if (n < N) WT[(size_t)n * K + k] = (_Float16)W[(size_t)k * N + n];
}

__global__ void copy_row(const float* __restrict__ W1, float* __restrict__ w1row, int N) {
    const int n = blockIdx.x * 256 + threadIdx.x;
    if (n < N) w1row[n] = W1[(size_t)1024 * N + n];
}

__global__ void init_h(const float* __restrict__ h0, float* __restrict__ hstate,
                       _Float16* __restrict__ x, int n) {
    const int i = blockIdx.x * 256 + threadIdx.x;
    if (i < n) {
        const float v = h0[i];
        hstate[i] = v;
        x[i] = (_Float16)v;
    }
}

// ---------------- launch ----------------
extern "C" void kernel_launch(void* const* d_in, const int* in_sizes, int n_in,
                              void* d_out, int out_size, void* d_ws, size_t ws_size,
                              hipStream_t stream) {
    const int B = 4096, H = 1024, H2 = 2048;

    const float* h0 = (const float*)d_in[0];
    const float* W1 = (const float*)d_in[1];  // (1025, 2048)
    const float* b1 = (const float*)d_in[2];  // (2048,)
    const float* W2 = (const float*)d_in[3];  // (2048, 2048)
    const float* b2 = (const float*)d_in[4];  // (2048,)
    const float* W3 = (const float*)d_in[5];  // (2048, 1024)
    const float* b3 = (const float*)d_in[6];  // (1024,)

    float* hstate = (float*)d_out;            // B*H fp32 state, final answer

    char* ws = (char*)d_ws;
    _Float16* x    = (_Float16*)ws; ws += (size_t)B * H  * 2;  // GEMM1 input
    _Float16* a1   = (_Float16*)ws; ws += (size_t)B * H2 * 2;  // layer-1 act
    _Float16* a2   = (_Float16*)ws; ws += (size_t)B * H2 * 2;  // layer-2 act
    float*    accb = (float*)ws;    ws += (size_t)B * H  * 4;  // RK4 k-accum
    _Float16* W1T  = (_Float16*)ws; ws += (size_t)H2 * H  * 2; // (2048,1024)
    _Float16* W2T  = (_Float16*)ws; ws += (size_t)H2 * H2 * 2; // (2048,2048)
    _Float16* W3T  = (_Float16*)ws; ws += (size_t)H  * H2 * 2; // (1024,2048)
    float*   w1row = (float*)ws;    ws += (size_t)H2 * 4;      // t-row of W1, fp32

    // weight conversion + transpose (runs every call; weights restored by harness)
    convT<<<dim3(H2 / 256, H),  256, 0, stream>>>(W1, W1T, H,  H2);
    convT<<<dim3(H2 / 256, H2), 256, 0, stream>>>(W2, W2T, H2, H2);
    convT<<<dim3(H  / 256, H2), 256, 0, stream>>>(W3, W3T, H2, H);
    copy_row<<<dim3(H2 / 256), 256, 0, stream>>>(W1, w1row, H2);
    init_h<<<dim3((B * H + 255) / 256), 256, 0, stream>>>(h0, hstate, x, B * H);

    const float dt  = 0.1f;
    const float dt2 = 0.05f;
    const float dt6 = dt / 6.0f;

    const dim3 blk(256);
    const dim3 g1grid(B / 128, H2 / 128);   // (32,16) = 512 blocks
    const dim3 g2grid(B / 128, H2 / 128);   // (32,16) = 512 blocks
    const dim3 g3grid(B / 64,  H  / 128);   // (64,8)  = 512 blocks

    for (int s = 0; s < 10; ++s) {
        const float ti = (float)s * dt;

        // k1 = f(ti, h)
        gemm_bias_tanh<true ><<<g1grid, blk, 0, stream>>>(x,  W1T, a1, b1, w1row, ti,        H2, H);
        gemm_bias_tanh<false><<<g2grid, blk, 0, stream>>>(a1, W2T, a2, b2, nullptr, 0.f,     H2, H2);
        gemm_k_stage<<<g3grid, blk, 0, stream>>>(a2, W3T, b3, hstate, accb, x, 0, dt2, dt6,  H,  H2);

        // k2 = f(ti+dt/2, h + dt/2*k1)
        gemm_bias_tanh<true ><<<g1grid, blk, 0, stream>>>(x,  W1T, a1, b1, w1row, ti + dt2,  H2, H);
        gemm_bias_tanh<false><<<g2grid, blk, 0, stream>>>(a1, W2T, a2, b2, nullptr, 0.f,     H2, H2);
        gemm_k_stage<<<g3grid, blk, 0, stream>>>(a2, W3T, b3, hstate, accb, x, 1, dt2, dt6,  H,  H2);

        // k3 = f(ti+dt/2, h + dt/2*k2)
        gemm_bias_tanh<true ><<<g1grid, blk, 0, stream>>>(x,  W1T, a1, b1, w1row, ti + dt2,  H2, H);
        gemm_bias_tanh<false><<<g2grid, blk, 0, stream>>>(a1, W2T, a2, b2, nullptr, 0.f,     H2, H2);
        gemm_k_stage<<<g3grid, blk, 0, stream>>>(a2, W3T, b3, hstate, accb, x, 2, dt,  dt6,  H,  H2);

        // k4 = f(ti+dt, h + dt*k3); h += dt/6*(k1+2k2+2k3+k4)
        gemm_bias_tanh<true ><<<g1grid, blk, 0, stream>>>(x,  W1T, a1, b1, w1row, ti + dt,   H2, H);
        gemm_bias_tanh<false><<<g2grid, blk, 0, stream>>>(a1, W2T, a2, b2, nullptr, 0.f,     H2, H2);
        gemm_k_stage<<<g3grid, blk, 0, stream>>>(a2, W3T, b3, hstate, accb, x, 3, dt,  dt6,  H,  H2);
    }
}